// Round 1
// 167.362 us; speedup vs baseline: 1.0802x; 1.0802x over previous
//
#include <hip/hip_runtime.h>

// Problem: y = relu(x @ (w1*m)^T + b1) @ (w2*m^T)^T + b2
// x:[131072,256] f32, w1:[1024,256], b1:[1024], w2:[256,1024], b2:[256], mask:[1024,256] i32
// Fused over hidden chunks of 32; bf16 MFMA 32x32x16 (2x FLOP per LDS B-read vs 16x16x32);
// 32 rows/wave (MT=128) to halve LDS-broadcast traffic per row. Weights pre-swizzled to
// 32x32x16 B-frag order. Hc scratch XOR-swizzled (bank-conflict-free b128 reads).

#define D_MODEL 256
#define D_HID   1024
#define MT      128     // rows per block (4 waves x 32 rows)
#define NCHUNK  32      // hidden chunks of 32
#define CHUNK_ELEMS 8192 // 32*256 bf16 elems per chunk per weight (16 KB)

typedef __attribute__((ext_vector_type(8))) short short8;
typedef __attribute__((ext_vector_type(16))) float f32x16;

__device__ __forceinline__ unsigned short f2bf(float f) {
  union { float f; unsigned int u; } v; v.f = f;
  unsigned int u = v.u;
  return (unsigned short)((u + 0x7FFFu + ((u >> 16) & 1u)) >> 16);  // RNE
}

__device__ __forceinline__ void async16(void* lds, const void* g) {
  __builtin_amdgcn_global_load_lds(
      (const __attribute__((address_space(1))) unsigned int*)g,
      (__attribute__((address_space(3))) unsigned int*)lds,
      16, 0, 0);
}

// ---------------- prep: mask+cast+swizzle weights into 32x32x16 B-frag order --------
// W1p slot t = (c*16+kf)*64+lane holds W1eff[h=c*32+(lane&31)][k=kf*16+(lane>>5)*8+j], j=0..7
// W2p slot s = ((c*8+cf)*2+kf2)*64+lane holds W2eff[n=cf*32+(lane&31)][h=c*32+kf2*16+(lane>>5)*8+j]
__global__ __launch_bounds__(256) void prep_weights(
    const float* __restrict__ w1, const float* __restrict__ w2,
    const int* __restrict__ mask,
    unsigned short* __restrict__ W1p, unsigned short* __restrict__ W2p)
{
  int t = blockIdx.x * 256 + threadIdx.x;   // 0..65535
  if (t < 32768) {
    int c    = t >> 10;
    int kf   = (t >> 6) & 15;
    int lane = t & 63;
    int h = c * 32 + (lane & 31);
    int k = kf * 16 + (lane >> 5) * 8;
    const float* wp = w1 + h * 256 + k;
    const int*   mp = mask + h * 256 + k;
    short8 v;
    #pragma unroll
    for (int j = 0; j < 8; ++j) v[j] = (short)(mp[j] ? f2bf(wp[j]) : 0);
    *(short8*)(W1p + (size_t)t * 8) = v;
  } else {
    int s    = t - 32768;
    int c    = s >> 10;
    int cf   = (s >> 7) & 7;
    int kf2  = (s >> 6) & 1;
    int lane = s & 63;
    int n = cf * 32 + (lane & 31);
    int h = c * 32 + kf2 * 16 + (lane >> 5) * 8;
    short8 v;
    #pragma unroll
    for (int j = 0; j < 8; ++j)
      v[j] = (short)(mask[(h + j) * 256 + n] ? f2bf(w2[n * 1024 + h + j]) : 0);
    *(short8*)(W2p + (size_t)s * 8) = v;
  }
}

// ---------------- fused main kernel ----------------
__global__ __launch_bounds__(256, 2) void ffd_fused(
    const float* __restrict__ X, const float* __restrict__ b1,
    const float* __restrict__ b2,
    const unsigned short* __restrict__ W1p, const unsigned short* __restrict__ W2p,
    float* __restrict__ Y)
{
  __shared__ unsigned short sW1[CHUNK_ELEMS];   // 16 KB, B-frag order
  __shared__ unsigned short sW2[CHUNK_ELEMS];   // 16 KB, B-frag order
  __shared__ unsigned short sHc[4][1024];       // per-wave 32x32 bf16, XOR-swizzled

  const int tid  = threadIdx.x;
  const int lane = tid & 63;
  const int w    = tid >> 6;
  const int l32  = lane & 31;
  const int q2   = lane >> 5;

  const long rowBase = (long)blockIdx.x * MT + w * 32;

  // X A-fragments (full K=256) in registers: xf[kf][j] = X[row][kf*16 + q2*8 + j]
  short8 xf[16];
  const float* xrow = X + (rowBase + l32) * D_MODEL;
  #pragma unroll
  for (int kf = 0; kf < 16; ++kf) {
    const float4 f0 = *(const float4*)(xrow + kf * 16 + q2 * 8);
    const float4 f1 = *(const float4*)(xrow + kf * 16 + q2 * 8 + 4);
    short8 v;
    v[0] = (short)f2bf(f0.x); v[1] = (short)f2bf(f0.y);
    v[2] = (short)f2bf(f0.z); v[3] = (short)f2bf(f0.w);
    v[4] = (short)f2bf(f1.x); v[5] = (short)f2bf(f1.y);
    v[6] = (short)f2bf(f1.z); v[7] = (short)f2bf(f1.w);
    xf[kf] = v;
  }

  f32x16 acc[8];
  #pragma unroll
  for (int i = 0; i < 8; ++i) {
    #pragma unroll
    for (int j = 0; j < 16; ++j) acc[i][j] = 0.f;
  }

  unsigned short* sHw = sHc[w];
  const int xorw = (l32 & 6) << 2;   // read-side XOR (row = l32), u16 units

  for (int c = 0; c < NCHUNK; ++c) {
    __syncthreads();   // all waves done reading sW1/sW2 of previous chunk
    {
      const unsigned short* g1 = W1p + (size_t)c * CHUNK_ELEMS + tid * 8;
      const unsigned short* g2 = W2p + (size_t)c * CHUNK_ELEMS + tid * 8;
      #pragma unroll
      for (int i = 0; i < 4; ++i) {
        async16(&sW1[i * 2048 + tid * 8], g1 + i * 2048);
        async16(&sW2[i * 2048 + tid * 8], g2 + i * 2048);
      }
    }
    const float bb = b1[c * 32 + l32];
    __syncthreads();   // staging complete (vmcnt(0) drained by compiler before barrier)

    // fc1: Hc[32 rows (this wave)][32 hidden] = X(regs) @ W1c^T
    f32x16 hh;
    #pragma unroll
    for (int j = 0; j < 16; ++j) hh[j] = 0.f;
    #pragma unroll
    for (int kf = 0; kf < 16; ++kf) {
      short8 bf = *(const short8*)&sW1[kf * 512 + lane * 8];
      hh = __builtin_amdgcn_mfma_f32_32x32x16_bf16(xf[kf], bf, hh, 0, 0, 0);
    }

    // bias + relu, C-layout -> XOR-swizzled row-major bf16 scratch (wave-private)
    #pragma unroll
    for (int r = 0; r < 16; ++r) {
      int rr = (r & 3) + 8 * (r >> 2) + 4 * q2;
      float v = hh[r] + bb;
      v = v > 0.f ? v : 0.f;
      sHw[(rr * 32 + l32) ^ ((rr & 6) << 2)] = f2bf(v);
    }
    __threadfence_block();   // order ds_write -> ds_read within the wave

    // fc2: acc[32 rows][256 cols] += Hc @ W2c^T   (K = 32 = two 32x32x16 steps)
    #pragma unroll
    for (int kf2 = 0; kf2 < 2; ++kf2) {
      short8 af = *(const short8*)&sHw[(l32 * 32 + kf2 * 16 + q2 * 8) ^ xorw];
      #pragma unroll
      for (int cf = 0; cf < 8; ++cf) {
        short8 bf2 = *(const short8*)&sW2[(cf * 2 + kf2) * 512 + lane * 8];
        acc[cf] = __builtin_amdgcn_mfma_f32_32x32x16_bf16(af, bf2, acc[cf], 0, 0, 0);
      }
    }
  }

  // epilogue: + b2, store fp32
  #pragma unroll
  for (int cf = 0; cf < 8; ++cf) {
    int col = cf * 32 + l32;
    float bias = b2[col];
    #pragma unroll
    for (int r = 0; r < 16; ++r) {
      long row = rowBase + (r & 3) + 8 * (r >> 2) + 4 * q2;
      Y[row * D_MODEL + col] = acc[cf][r] + bias;
    }
  }
}

extern "C" void kernel_launch(void* const* d_in, const int* in_sizes, int n_in,
                              void* d_out, int out_size, void* d_ws, size_t ws_size,
                              hipStream_t stream) {
  const float* x    = (const float*)d_in[0];
  const float* w1   = (const float*)d_in[1];
  const float* b1   = (const float*)d_in[2];
  const float* w2   = (const float*)d_in[3];
  const float* b2   = (const float*)d_in[4];
  const int*   mask = (const int*)d_in[5];

  unsigned short* W1p = (unsigned short*)d_ws;          // 512 KB
  unsigned short* W2p = W1p + (size_t)D_HID * D_MODEL;  // 512 KB
  float* Y = (float*)d_out;

  prep_weights<<<256, 256, 0, stream>>>(w1, w2, mask, W1p, W2p);
  ffd_fused<<<131072 / MT, 256, 0, stream>>>(x, b1, b2, W1p, W2p, Y);
}